// Round 25
// baseline (191.886 us; speedup 1.0000x reference)
//
#include <hip/hip_runtime.h>
#include <hip/hip_bf16.h>

#define EPSV 1e-5f

// workspace layout: [wB2][xTp][stats]
#define WB2_ELEMS (2*4*36*256*32)          // [p][nt(4)][kt(36)][nl(256)][kk(32)] bf16
#define WB2_BYTES ((size_t)WB2_ELEMS*2)    // 4,718,592
#define XTP_ELEMS (8*68*68*128)            // padded channels-last x, bf16
#define XTP_BYTES ((size_t)XTP_ELEMS*2)    // 9,469,952
#define STATS_OFF (WB2_BYTES + XTP_BYTES)  // 1024 float2 partials

// k_conv dynamic LDS: 4 dbuf x (A 16 KB + B 16 KB) = 128 KB
#define CONV_LDS_BYTES (131072)

typedef __attribute__((ext_vector_type(8))) short short8;
typedef __attribute__((ext_vector_type(4))) float f32x4;

__device__ __forceinline__ void gload_lds16(const void* g, void* l) {
    __builtin_amdgcn_global_load_lds(
        (const __attribute__((address_space(1))) void*)g,
        (__attribute__((address_space(3))) void*)l, 16, 0, 0);
}

// ---------------------------------------------------------------------------
// x [8][128][64][64] f32  ->  xTp [8][68][68][128] bf16 (2-px zero halo)
__global__ __launch_bounds__(256) void k_xpad(const float* __restrict__ x,
                                              __hip_bfloat16* __restrict__ xTp) {
    int bh = blockIdx.x; int b = bh >> 6, h = bh & 63;
    __shared__ __hip_bfloat16 tile[64][130];
    int t = threadIdx.x;
#pragma unroll
    for (int i = 0; i < 32; ++i) {
        int e = (i << 8) + t; int w = e & 63; int ci = e >> 6;
        tile[w][ci] = __float2bfloat16(x[(((size_t)(b*128 + ci))*64 + h)*64 + w]);
    }
    __syncthreads();
    __hip_bfloat16* dst = xTp + ((size_t)((b*68 + h + 2)*68 + 2))*128;
#pragma unroll
    for (int i = 0; i < 32; ++i) {
        int e = (i << 8) + t; int ci = e & 127; int w = e >> 7;
        dst[w*128 + ci] = tile[w][ci];
    }
}

// ---------------------------------------------------------------------------
// w_mid [128][16][128][3][3] f32 -> wB2 [p][nt(4)][kt(36)][nl(256)][kk(32)]
// column meaning: n = c_outer*64 + m*4 + c_inner (R24-proven remap)
__global__ void k_wrepack(const float* __restrict__ w_mid,
                          __hip_bfloat16* __restrict__ wB2) {
    int idx = blockIdx.x * 256 + threadIdx.x;
    if (idx >= WB2_ELEMS) return;
    int kk  = idx & 31;
    int nl  = (idx >> 5) & 255;
    int q   = idx >> 13;             // (p*4+nt)*36 + kt
    int kt  = q % 36;
    int pnt = q / 36;                // 0..7
    int nt  = pnt & 3, p = pnt >> 2;
    int c_local = (nt*4 + (nl >> 6))*4 + (nl & 3);   // c_outer*4 + c_inner
    int m = (nl >> 2) & 15;
    int c = 2*c_local + p;
    int k = kt*32 + kk;
    int tap = k >> 7, ci = k & 127;
    wB2[idx] = __float2bfloat16(w_mid[((size_t)((c*16 + m)*128 + ci))*9 + tap]);
}

// ---------------------------------------------------------------------------
// Implicit-GEMM conv — R24 skeleton with the two pipes UN-SERIALIZED:
// per ktile: {12 plain ds_reads (compiler emits progressive counted lgkm) ->
// 4 gload_lds staging (kt+2) -> 32 MFMA -> vmcnt(4) -> s_barrier ->
// sched_barrier}. Mid-ktile barrier and blanket lgkmcnt(0) removed — waves
// drift within a ktile so the LDS pipe runs under the matrix pipe.
// WAR audit: staging targets dbuf (kt+2)&3, last read 2 boundary-barriers
// earlier. Visibility: per-wave vmcnt before the boundary barrier (R24
// contract, unchanged). Epilogue = R24's remapped 2-shuffle version.
__global__ __launch_bounds__(512, 2) void k_conv(
    const __hip_bfloat16* __restrict__ xTp,
    const __hip_bfloat16* __restrict__ wB2,
    const float* __restrict__ w_pt,
    const float* __restrict__ b_pt,
    float* __restrict__ y) {
    extern __shared__ char smem[];
    __hip_bfloat16* Ae = (__hip_bfloat16*)smem;              // 4 x 8192 elems
    __hip_bfloat16* Be = (__hip_bfloat16*)(smem + 65536);    // 4 x 8192 elems

    const int combo = blockIdx.x & 7;      // XCD: one (p, nt) each
    const int p  = combo & 1;
    const int nt = combo >> 1;             // 0..3
    const int mt = blockIdx.x >> 3;        // 0..127 (256 spatial rows each)
    const int dil = 1 + p;

    const int t = threadIdx.x;             // 0..511
    const int lane = t & 63;
    const int wave = t >> 6;               // 0..7
    const int wm = wave >> 2;              // 0..1
    const int wn = wave & 3;               // 0..3
    const int lm = lane & 15, lg = lane >> 4;

    // ---- staging addressing (R21/R24-verbatim) ----
    const int rsub = t >> 2;                              // row 0..127
    const int ksub = (((t & 3) ^ ((t >> 3) & 3)) << 3);   // src-side swizzled slot
    const __hip_bfloat16* abase0;
    const __hip_bfloat16* abase1;
    {
        int s0 = mt*256 + rsub;
        int s1 = s0 + 128;
        abase0 = xTp + ((size_t)(((s0>>12)*68 + ((s0>>6)&63) + 2)*68 + (s0&63) + 2))*128 + ksub;
        abase1 = xTp + ((size_t)(((s1>>12)*68 + ((s1>>6)&63) + 2)*68 + (s1&63) + 2))*128 + ksub;
    }
    const __hip_bfloat16* bbase = wB2 + (size_t)(p*4 + nt)*(36*8192)
                                + rsub*32 + ksub;

    // ---- ds-read offsets (R21/R24-verbatim swizzle) ----
    const int sslot = (lg ^ ((lm >> 1) & 3)) << 3;
    const int aoffb = (wm*128 + lm)*32 + sslot;     // + i*512 + dbuf*8192
    const int boffb = (wn*64 + lm)*32 + sslot;      // + j*512 + dbuf*8192

    f32x4 acc[8][4];
#pragma unroll
    for (int i = 0; i < 8; ++i)
#pragma unroll
        for (int j = 0; j < 4; ++j) acc[i][j] = (f32x4){0.f, 0.f, 0.f, 0.f};

    // ---- prologue: stage kt0 -> dbuf0, kt1 -> dbuf1 (8 loads), vmcnt(4) ----
    {
        const int t0 = -dil*8832;    // tap 0: kh=-1, kw=-1; ci0 = 0
        gload_lds16(abase0 + t0,      smem           + (0*512 + t)*16);
        gload_lds16(abase1 + t0,      smem           + (1*512 + t)*16);
        gload_lds16(bbase,            smem + 65536   + (0*512 + t)*16);
        gload_lds16(bbase + 4096,     smem + 65536   + (1*512 + t)*16);
        gload_lds16(abase0 + t0 + 32, smem + 16384   + (0*512 + t)*16);
        gload_lds16(abase1 + t0 + 32, smem + 16384   + (1*512 + t)*16);
        gload_lds16(bbase + 8192,     smem + 81920   + (0*512 + t)*16);
        gload_lds16(bbase + 12288,    smem + 81920   + (1*512 + t)*16);
    }
    asm volatile("s_waitcnt vmcnt(4)" ::: "memory");   // kt0 resident, kt1 in flight
    __builtin_amdgcn_s_barrier();
    __builtin_amdgcn_sched_barrier(0);

    // ---- K-loop: kt = 4*vv + ss, ONE barrier per ktile ----
#pragma unroll 1
    for (int vv = 0; vv < 9; ++vv) {
        const int q3c = (vv*11) >> 5;
        const int toff_c = dil*128*((q3c - 1)*68 + (vv - 3*q3c - 1));
        const int vn = vv + 1;
        const int q3n = (vn*11) >> 5;
        const int toff_n = dil*128*((q3n - 1)*68 + (vn - 3*q3n - 1));
#pragma unroll
        for (int ss = 0; ss < 4; ++ss) {
            const int d  = ss;                 // dbuf of ktile kt (static)
            const int d2 = (ss + 2) & 3;       // dbuf staged (static)
            const bool do_stage = (vv < 8) || (ss < 2);   // kt+2 < 36
            // 1. all fragment reads for this ktile (plain loads; compiler
            //    emits progressive counted lgkmcnt before each dependent MFMA)
            short8 bf[4], af[8];
#pragma unroll
            for (int j = 0; j < 4; ++j)
                bf[j] = *(const short8*)(Be + d*8192 + boffb + j*512);
#pragma unroll
            for (int ii = 0; ii < 8; ++ii)
                af[ii] = *(const short8*)(Ae + d*8192 + aoffb + ii*512);
            // 2. staging for ktile kt+2 (4 gload_lds into dbuf d2)
            if (do_stage) {
                const int aoff = (ss < 2) ? (toff_c + (ss + 2)*32)
                                          : (toff_n + (ss - 2)*32);
                gload_lds16(abase0 + aoff, smem + d2*16384 + (0*512 + t)*16);
                gload_lds16(abase1 + aoff, smem + d2*16384 + (1*512 + t)*16);
                const size_t bo = (size_t)(4*vv + ss + 2)*8192;
                gload_lds16(bbase + bo,        smem + 65536 + d2*16384 + (0*512 + t)*16);
                gload_lds16(bbase + bo + 4096, smem + 65536 + d2*16384 + (1*512 + t)*16);
            }
            // 3. MFMA cluster (waits interleave with LDS returns)
            __builtin_amdgcn_s_setprio(1);
#pragma unroll
            for (int ii = 0; ii < 8; ++ii)
#pragma unroll
                for (int j = 0; j < 4; ++j)
                    acc[ii][j] = __builtin_amdgcn_mfma_f32_16x16x32_bf16(
                        af[ii], bf[j], acc[ii][j], 0, 0, 0);
            __builtin_amdgcn_s_setprio(0);
            // 4-6. ktile boundary: kt+1 resident, visible to all waves
            if (vv == 8 && ss >= 2) asm volatile("s_waitcnt vmcnt(0)" ::: "memory");
            else                    asm volatile("s_waitcnt vmcnt(4)" ::: "memory");
            __builtin_amdgcn_s_barrier();
            __builtin_amdgcn_sched_barrier(0);
        }
    }

    // ---- epilogue (R24-verbatim): leaky -> *w_pt -> sum over j -> 2 shuffles
    {
        const int ci_ = lm & 3;
        const int mg  = lm >> 2;                       // m sub-index in lanes
        const int c   = (((nt*4 + wn)*4 + ci_) << 1) + p;
        const float bp = b_pt[c];
        float wpj[4];
#pragma unroll
        for (int j = 0; j < 4; ++j)
            wpj[j] = w_pt[c*16 + j*4 + mg];
#pragma unroll
        for (int i = 0; i < 8; ++i) {
#pragma unroll
            for (int r = 0; r < 4; ++r) {
                float s = 0.f;
#pragma unroll
                for (int j = 0; j < 4; ++j) {
                    float v = acc[i][j][r];
                    v = v >= 0.f ? v : 0.1f*v;
                    s += v * wpj[j];
                }
                s += __shfl_xor(s, 4);
                s += __shfl_xor(s, 8);
                if (mg == 0) {
                    int srow = mt*256 + wm*128 + i*16 + lg*4 + r;
                    int b = srow >> 12, hw = srow & 4095;
                    y[(size_t)(b*128 + c)*4096 + hw] = s + bp;
                }
            }
        }
    }
}

// ---------------------------------------------------------------------------
// per-(b,c)-plane partial sums (float4 loads, no atomics, deterministic)
__global__ __launch_bounds__(256) void k_ystat(const float* __restrict__ y,
                                               float2* __restrict__ partials) {
    int P = blockIdx.x;                 // plane = b*128 + c
    const float4* base = (const float4*)(y + (size_t)P*4096);
    int t = threadIdx.x;
    float s = 0.f, s2 = 0.f;
#pragma unroll
    for (int i = 0; i < 4; ++i) {
        float4 v = base[t + i*256];
        s  += v.x + v.y + v.z + v.w;
        s2 += v.x*v.x + v.y*v.y + v.z*v.z + v.w*v.w;
    }
#pragma unroll
    for (int o = 32; o; o >>= 1) { s += __shfl_down(s, o); s2 += __shfl_down(s2, o); }
    __shared__ float ss[4], ss2[4];
    if ((t & 63) == 0) { ss[t >> 6] = s; ss2[t >> 6] = s2; }
    __syncthreads();
    if (t == 0)
        partials[P] = make_float2(ss[0]+ss[1]+ss[2]+ss[3], ss2[0]+ss2[1]+ss2[2]+ss2[3]);
}

// BN finalize + apply + ReLU. Block covers 256 float4 = quarter of one plane.
__global__ __launch_bounds__(256) void k_bn_apply(float* __restrict__ y,
                                                  const float2* __restrict__ partials,
                                                  const float* __restrict__ gamma,
                                                  const float* __restrict__ beta) {
    int bid = blockIdx.x;
    int c = (bid >> 2) & 127;
    float s = 0.f, s2 = 0.f;
#pragma unroll
    for (int b = 0; b < 8; ++b) {
        float2 pr = partials[b*128 + c];
        s += pr.x; s2 += pr.y;
    }
    float mean = s * (1.f/32768.f);
    float var  = s2 * (1.f/32768.f) - mean*mean;
    float scale = gamma[c] * rsqrtf(var + EPSV);
    float shift = beta[c] - mean*scale;
    float4* y4 = (float4*)y;
    int idx = bid*256 + threadIdx.x;
    float4 v = y4[idx];
    v.x = fmaxf(v.x*scale + shift, 0.f);
    v.y = fmaxf(v.y*scale + shift, 0.f);
    v.z = fmaxf(v.z*scale + shift, 0.f);
    v.w = fmaxf(v.w*scale + shift, 0.f);
    y4[idx] = v;
}

// ---------------------------------------------------------------------------
extern "C" void kernel_launch(void* const* d_in, const int* in_sizes, int n_in,
                              void* d_out, int out_size, void* d_ws, size_t ws_size,
                              hipStream_t stream) {
    const float* x     = (const float*)d_in[0];
    const float* w_mid = (const float*)d_in[1];
    const float* w_pt  = (const float*)d_in[2];
    const float* b_pt  = (const float*)d_in[3];
    const float* gamma = (const float*)d_in[4];
    const float* beta  = (const float*)d_in[5];
    float* y = (float*)d_out;

    __hip_bfloat16* wB2 = (__hip_bfloat16*)d_ws;
    __hip_bfloat16* xTp = (__hip_bfloat16*)((char*)d_ws + WB2_BYTES);
    float2* partials    = (float2*)((char*)d_ws + STATS_OFF);

    // opt in to >64 KB dynamic LDS for k_conv (host-side, graph-capture-safe)
    (void)hipFuncSetAttribute((const void*)k_conv,
                              hipFuncAttributeMaxDynamicSharedMemorySize,
                              CONV_LDS_BYTES);

    hipMemsetAsync(xTp, 0, XTP_BYTES, stream);                  // zero halo
    k_xpad<<<512, 256, 0, stream>>>(x, xTp);
    k_wrepack<<<(WB2_ELEMS + 255) / 256, 256, 0, stream>>>(w_mid, wB2);
    k_conv<<<1024, 512, CONV_LDS_BYTES, stream>>>(xTp, wB2, w_pt, b_pt, y);
    k_ystat<<<1024, 256, 0, stream>>>(y, partials);
    k_bn_apply<<<4096, 256, 0, stream>>>(y, partials, gamma, beta);
}

// Round 26
// 187.615 us; speedup vs baseline: 1.0228x; 1.0228x over previous
//
#include <hip/hip_runtime.h>
#include <hip/hip_bf16.h>

#define EPSV 1e-5f

// workspace layout: [wB2][xTp][partials]
#define WB2_ELEMS (2*4*36*256*32)          // [p][nt(4)][kt(36)][nl(256)][kk(32)] bf16
#define WB2_BYTES ((size_t)WB2_ELEMS*2)    // 4,718,592
#define XTP_ELEMS (8*68*68*128)            // padded channels-last x, bf16
#define XTP_BYTES ((size_t)XTP_ELEMS*2)    // 9,469,952
#define STATS_OFF (WB2_BYTES + XTP_BYTES)  // 128 c x 128 mt float2 = 128 KB

// k_conv dynamic LDS: 4 dbuf x (A 16 KB + B 16 KB) = 128 KB
#define CONV_LDS_BYTES (131072)

typedef __attribute__((ext_vector_type(8))) short short8;
typedef __attribute__((ext_vector_type(4))) float f32x4;

__device__ __forceinline__ void gload_lds16(const void* g, void* l) {
    __builtin_amdgcn_global_load_lds(
        (const __attribute__((address_space(1))) void*)g,
        (__attribute__((address_space(3))) void*)l, 16, 0, 0);
}

// ---------------------------------------------------------------------------
// Fused prep: blocks 0..511 = xpad (x -> padded channels-last bf16);
// blocks 512..1663 = wrepack (8 elems/thread, short8 stores).
__global__ __launch_bounds__(256) void k_prep(const float* __restrict__ x,
                                              const float* __restrict__ w_mid,
                                              __hip_bfloat16* __restrict__ xTp,
                                              __hip_bfloat16* __restrict__ wB2) {
    int t = threadIdx.x;
    if (blockIdx.x < 512) {
        int bh = blockIdx.x; int b = bh >> 6, h = bh & 63;
        __shared__ __hip_bfloat16 tile[64][130];
#pragma unroll
        for (int i = 0; i < 32; ++i) {
            int e = (i << 8) + t; int w = e & 63; int ci = e >> 6;
            tile[w][ci] = __float2bfloat16(x[(((size_t)(b*128 + ci))*64 + h)*64 + w]);
        }
        __syncthreads();
        __hip_bfloat16* dst = xTp + ((size_t)((b*68 + h + 2)*68 + 2))*128;
#pragma unroll
        for (int i = 0; i < 32; ++i) {
            int e = (i << 8) + t; int ci = e & 127; int w = e >> 7;
            dst[w*128 + ci] = tile[w][ci];
        }
    } else {
        // wrepack: n = c_outer*64 + m*4 + c_inner (R24-proven remap), 8/thread
        int e8 = (blockIdx.x - 512)*256 + t;        // 0..294911
        int base = e8 * 8;
        int kk0 = base & 31;
        int nl  = (base >> 5) & 255;
        int q   = base >> 13;            // (p*4+nt)*36 + kt
        int kt  = q % 36;
        int pnt = q / 36;                // 0..7
        int nt  = pnt & 3, p = pnt >> 2;
        int c_local = (nt*4 + (nl >> 6))*4 + (nl & 3);
        int m = (nl >> 2) & 15;
        int c = 2*c_local + p;
        int tap = kt >> 2;
        int ci0 = ((kt & 3) << 5) + kk0;
        const float* src = w_mid + ((size_t)((c*16 + m)*128 + ci0))*9 + tap;
        short8 v;
#pragma unroll
        for (int e = 0; e < 8; ++e) {
            __hip_bfloat16 h = __float2bfloat16(src[e*9]);
            v[e] = *(short*)&h;
        }
        *(short8*)(wB2 + base) = v;
    }
}

// ---------------------------------------------------------------------------
// Implicit-GEMM conv — R24 body (best: 150.7 us) + FUSED BN partial stats:
// epilogue accumulates per-channel (sum, sumsq) over this block's 256 rows
// (2 extra shuffles + 32-entry LDS reduce, smem reused) and writes
// partials[c*128 + mt] — removes the k_ystat pass over y entirely.
__global__ __launch_bounds__(512, 2) void k_conv(
    const __hip_bfloat16* __restrict__ xTp,
    const __hip_bfloat16* __restrict__ wB2,
    const float* __restrict__ w_pt,
    const float* __restrict__ b_pt,
    float* __restrict__ y,
    float2* __restrict__ partials) {
    extern __shared__ char smem[];
    __hip_bfloat16* Ae = (__hip_bfloat16*)smem;              // 4 x 8192 elems
    __hip_bfloat16* Be = (__hip_bfloat16*)(smem + 65536);    // 4 x 8192 elems

    const int combo = blockIdx.x & 7;      // XCD: one (p, nt) each
    const int p  = combo & 1;
    const int nt = combo >> 1;             // 0..3
    const int mt = blockIdx.x >> 3;        // 0..127 (256 spatial rows each)
    const int dil = 1 + p;

    const int t = threadIdx.x;             // 0..511
    const int lane = t & 63;
    const int wave = t >> 6;               // 0..7
    const int wm = wave >> 2;              // 0..1
    const int wn = wave & 3;               // 0..3
    const int lm = lane & 15, lg = lane >> 4;

    // ---- staging addressing (R21/R24-verbatim) ----
    const int rsub = t >> 2;                              // row 0..127
    const int ksub = (((t & 3) ^ ((t >> 3) & 3)) << 3);   // src-side swizzled slot
    const __hip_bfloat16* abase0;
    const __hip_bfloat16* abase1;
    {
        int s0 = mt*256 + rsub;
        int s1 = s0 + 128;
        abase0 = xTp + ((size_t)(((s0>>12)*68 + ((s0>>6)&63) + 2)*68 + (s0&63) + 2))*128 + ksub;
        abase1 = xTp + ((size_t)(((s1>>12)*68 + ((s1>>6)&63) + 2)*68 + (s1&63) + 2))*128 + ksub;
    }
    const __hip_bfloat16* bbase = wB2 + (size_t)(p*4 + nt)*(36*8192)
                                + rsub*32 + ksub;

    // ---- ds-read offsets (R21/R24-verbatim swizzle) ----
    const int sslot = (lg ^ ((lm >> 1) & 3)) << 3;
    const int aoffb = (wm*128 + lm)*32 + sslot;     // + i*512 + dbuf*8192
    const int boffb = (wn*64 + lm)*32 + sslot;      // + j*512 + dbuf*8192

    f32x4 acc[8][4];
#pragma unroll
    for (int i = 0; i < 8; ++i)
#pragma unroll
        for (int j = 0; j < 4; ++j) acc[i][j] = (f32x4){0.f, 0.f, 0.f, 0.f};

    // ---- prologue: stage kt0 -> dbuf0, kt1 -> dbuf1 (8 loads), vmcnt(4) ----
    {
        const int t0 = -dil*8832;    // tap 0: kh=-1, kw=-1; ci0 = 0
        gload_lds16(abase0 + t0,      smem           + (0*512 + t)*16);
        gload_lds16(abase1 + t0,      smem           + (1*512 + t)*16);
        gload_lds16(bbase,            smem + 65536   + (0*512 + t)*16);
        gload_lds16(bbase + 4096,     smem + 65536   + (1*512 + t)*16);
        gload_lds16(abase0 + t0 + 32, smem + 16384   + (0*512 + t)*16);
        gload_lds16(abase1 + t0 + 32, smem + 16384   + (1*512 + t)*16);
        gload_lds16(bbase + 8192,     smem + 81920   + (0*512 + t)*16);
        gload_lds16(bbase + 12288,    smem + 81920   + (1*512 + t)*16);
    }
    asm volatile("s_waitcnt vmcnt(4)" ::: "memory");   // kt0 resident, kt1 in flight
    __builtin_amdgcn_s_barrier();
    __builtin_amdgcn_sched_barrier(0);

    // ---- K-loop: kt = 4*vv + ss, 2 phases (q) per ktile (R24-verbatim) ----
#pragma unroll 1
    for (int vv = 0; vv < 9; ++vv) {
        const int q3c = (vv*11) >> 5;
        const int toff_c = dil*128*((q3c - 1)*68 + (vv - 3*q3c - 1));
        const int vn = vv + 1;
        const int q3n = (vn*11) >> 5;
        const int toff_n = dil*128*((q3n - 1)*68 + (vn - 3*q3n - 1));
#pragma unroll
        for (int ss = 0; ss < 4; ++ss) {
            const int d  = ss;                 // dbuf of ktile kt (static)
            const int d2 = (ss + 2) & 3;       // dbuf staged (static)
            const bool do_stage = (vv < 8) || (ss < 2);   // kt+2 < 36
            short8 bf[4];
            short8 af[4];
#pragma unroll
            for (int q = 0; q < 2; ++q) {
                if (q == 0) {
#pragma unroll
                    for (int j = 0; j < 4; ++j)
                        bf[j] = *(const short8*)(Be + d*8192 + boffb + j*512);
                }
#pragma unroll
                for (int ii = 0; ii < 4; ++ii)
                    af[ii] = *(const short8*)(Ae + d*8192 + aoffb + (q*4 + ii)*512);
                if (do_stage) {
                    if (q == 0) {
                        const int aoff = (ss < 2) ? (toff_c + (ss + 2)*32)
                                                  : (toff_n + (ss - 2)*32);
                        gload_lds16(abase0 + aoff, smem + d2*16384 + (0*512 + t)*16);
                        gload_lds16(abase1 + aoff, smem + d2*16384 + (1*512 + t)*16);
                    } else {
                        const size_t bo = (size_t)(4*vv + ss + 2)*8192;
                        gload_lds16(bbase + bo,        smem + 65536 + d2*16384 + (0*512 + t)*16);
                        gload_lds16(bbase + bo + 4096, smem + 65536 + d2*16384 + (1*512 + t)*16);
                    }
                }
                if (q == 1) {
                    if (ss == 2) {
                        if (vv == 8) asm volatile("s_waitcnt vmcnt(0)" ::: "memory");
                        else         asm volatile("s_waitcnt vmcnt(4)" ::: "memory");
                    } else {
                        asm volatile("s_waitcnt vmcnt(4)" ::: "memory");
                    }
                }
                __builtin_amdgcn_s_barrier();
                asm volatile("s_waitcnt lgkmcnt(0)" ::: "memory");
                __builtin_amdgcn_sched_barrier(0);
                __builtin_amdgcn_s_setprio(1);
#pragma unroll
                for (int ii = 0; ii < 4; ++ii)
#pragma unroll
                    for (int j = 0; j < 4; ++j)
                        acc[q*4 + ii][j] = __builtin_amdgcn_mfma_f32_16x16x32_bf16(
                            af[ii], bf[j], acc[q*4 + ii][j], 0, 0, 0);
                __builtin_amdgcn_s_setprio(0);
            }
        }
    }

    // ---- epilogue: leaky -> *w_pt -> sum over j -> 2 shuffles; fused stats ----
    {
        const int ci_ = lm & 3;
        const int mg  = lm >> 2;                       // m sub-index in lanes
        const int c   = (((nt*4 + wn)*4 + ci_) << 1) + p;
        const float bp = b_pt[c];
        float wpj[4];
#pragma unroll
        for (int j = 0; j < 4; ++j)
            wpj[j] = w_pt[c*16 + j*4 + mg];
        float ts = 0.f, ts2 = 0.f;
#pragma unroll
        for (int i = 0; i < 8; ++i) {
#pragma unroll
            for (int r = 0; r < 4; ++r) {
                float s = 0.f;
#pragma unroll
                for (int j = 0; j < 4; ++j) {
                    float v = acc[i][j][r];
                    v = v >= 0.f ? v : 0.1f*v;
                    s += v * wpj[j];
                }
                s += __shfl_xor(s, 4);
                s += __shfl_xor(s, 8);
                if (mg == 0) {
                    float val = s + bp;
                    int srow = mt*256 + wm*128 + i*16 + lg*4 + r;
                    int b = srow >> 12, hw = srow & 4095;
                    y[(size_t)(b*128 + c)*4096 + hw] = val;
                    ts  += val;
                    ts2 += val*val;
                }
            }
        }
        // reduce over lg (lanes differing in bits 4,5; lm preserved)
        ts  += __shfl_xor(ts, 16);  ts2 += __shfl_xor(ts2, 16);
        ts  += __shfl_xor(ts, 32);  ts2 += __shfl_xor(ts2, 32);
        __syncthreads();                       // K-loop LDS use fully done
        float2* red = (float2*)smem;           // 8 waves x 4 ci
        if (lg == 0 && mg == 0) red[wave*4 + ci_] = make_float2(ts, ts2);
        __syncthreads();
        if (t < 16) {
            int wn_ = t >> 2, ci2 = t & 3;
            float2 a0 = red[(0*4 + wn_)*4 + ci2];    // wm=0 wave
            float2 a1 = red[(1*4 + wn_)*4 + ci2];    // wm=1 wave
            int cc = (((nt*4 + wn_)*4 + ci2) << 1) + p;
            partials[cc*128 + mt] = make_float2(a0.x + a1.x, a0.y + a1.y);
        }
    }
}

// ---------------------------------------------------------------------------
// BN finalize (from 128 per-channel block-partials) + apply + ReLU.
// Block covers 256 float4 = quarter of one (b,c) plane.
__global__ __launch_bounds__(256) void k_bn_apply(float* __restrict__ y,
                                                  const float2* __restrict__ partials,
                                                  const float* __restrict__ gamma,
                                                  const float* __restrict__ beta) {
    int bid = blockIdx.x;
    int c = (bid >> 2) & 127;
    float s = 0.f, s2 = 0.f;
    const float2* pc = partials + c*128;
#pragma unroll 8
    for (int i = 0; i < 128; ++i) {
        float2 pr = pc[i];
        s += pr.x; s2 += pr.y;
    }
    float mean = s * (1.f/32768.f);
    float var  = s2 * (1.f/32768.f) - mean*mean;
    float scale = gamma[c] * rsqrtf(var + EPSV);
    float shift = beta[c] - mean*scale;
    float4* y4 = (float4*)y;
    int idx = bid*256 + threadIdx.x;
    float4 v = y4[idx];
    v.x = fmaxf(v.x*scale + shift, 0.f);
    v.y = fmaxf(v.y*scale + shift, 0.f);
    v.z = fmaxf(v.z*scale + shift, 0.f);
    v.w = fmaxf(v.w*scale + shift, 0.f);
    y4[idx] = v;
}

// ---------------------------------------------------------------------------
extern "C" void kernel_launch(void* const* d_in, const int* in_sizes, int n_in,
                              void* d_out, int out_size, void* d_ws, size_t ws_size,
                              hipStream_t stream) {
    const float* x     = (const float*)d_in[0];
    const float* w_mid = (const float*)d_in[1];
    const float* w_pt  = (const float*)d_in[2];
    const float* b_pt  = (const float*)d_in[3];
    const float* gamma = (const float*)d_in[4];
    const float* beta  = (const float*)d_in[5];
    float* y = (float*)d_out;

    __hip_bfloat16* wB2 = (__hip_bfloat16*)d_ws;
    __hip_bfloat16* xTp = (__hip_bfloat16*)((char*)d_ws + WB2_BYTES);
    float2* partials    = (float2*)((char*)d_ws + STATS_OFF);

    // opt in to >64 KB dynamic LDS for k_conv (host-side, graph-capture-safe)
    (void)hipFuncSetAttribute((const void*)k_conv,
                              hipFuncAttributeMaxDynamicSharedMemorySize,
                              CONV_LDS_BYTES);

    hipMemsetAsync(xTp, 0, XTP_BYTES, stream);                  // zero halo
    k_prep<<<1664, 256, 0, stream>>>(x, w_mid, xTp, wB2);
    k_conv<<<1024, 512, CONV_LDS_BYTES, stream>>>(xTp, wB2, w_pt, b_pt, y, partials);
    k_bn_apply<<<4096, 256, 0, stream>>>(y, partials, gamma, beta);
}

// Round 27
// 183.883 us; speedup vs baseline: 1.0435x; 1.0203x over previous
//
#include <hip/hip_runtime.h>
#include <hip/hip_bf16.h>

#define EPSV 1e-5f

// workspace layout: [wB2][xTp][partials]
#define WB2_ELEMS (2*4*36*256*32)          // [p][nt(4)][kt(36)][nl(256)][kk(32)] bf16
#define WB2_BYTES ((size_t)WB2_ELEMS*2)    // 4,718,592
#define XTP_ELEMS (8*68*68*128)            // padded channels-last x, bf16
#define XTP_BYTES ((size_t)XTP_ELEMS*2)    // 9,469,952
#define STATS_OFF (WB2_BYTES + XTP_BYTES)  // 128 c x 128 mt float2 = 128 KB

// k_conv dynamic LDS: 4 dbuf x (A 16 KB + B 16 KB) = 128 KB
#define CONV_LDS_BYTES (131072)

typedef __attribute__((ext_vector_type(8))) short short8;
typedef __attribute__((ext_vector_type(4))) float f32x4;

__device__ __forceinline__ void gload_lds16(const void* g, void* l) {
    __builtin_amdgcn_global_load_lds(
        (const __attribute__((address_space(1))) void*)g,
        (__attribute__((address_space(3))) void*)l, 16, 0, 0);
}

// ---------------------------------------------------------------------------
// Fused prep: blocks 0..511 = xpad interior; 512..1663 = wrepack (8/thread);
// 1664..1927 = zero the 1.06 MB halo strips (replaces the 9.5 MB memset).
__global__ __launch_bounds__(256) void k_prep(const float* __restrict__ x,
                                              const float* __restrict__ w_mid,
                                              __hip_bfloat16* __restrict__ xTp,
                                              __hip_bfloat16* __restrict__ wB2) {
    int t = threadIdx.x;
    if (blockIdx.x < 512) {
        int bh = blockIdx.x; int b = bh >> 6, h = bh & 63;
        __shared__ __hip_bfloat16 tile[64][130];
#pragma unroll
        for (int i = 0; i < 32; ++i) {
            int e = (i << 8) + t; int w = e & 63; int ci = e >> 6;
            tile[w][ci] = __float2bfloat16(x[(((size_t)(b*128 + ci))*64 + h)*64 + w]);
        }
        __syncthreads();
        __hip_bfloat16* dst = xTp + ((size_t)((b*68 + h + 2)*68 + 2))*128;
#pragma unroll
        for (int i = 0; i < 32; ++i) {
            int e = (i << 8) + t; int ci = e & 127; int w = e >> 7;
            dst[w*128 + ci] = tile[w][ci];
        }
    } else if (blockIdx.x < 1664) {
        // wrepack: n = c_outer*64 + m*4 + c_inner (R24-proven remap), 8/thread
        int e8 = (blockIdx.x - 512)*256 + t;        // 0..294911
        int base = e8 * 8;
        int kk0 = base & 31;
        int nl  = (base >> 5) & 255;
        int q   = base >> 13;            // (p*4+nt)*36 + kt
        int kt  = q % 36;
        int pnt = q / 36;                // 0..7
        int nt  = pnt & 3, p = pnt >> 2;
        int c_local = (nt*4 + (nl >> 6))*4 + (nl & 3);
        int m = (nl >> 2) & 15;
        int c = 2*c_local + p;
        int tap = kt >> 2;
        int ci0 = ((kt & 3) << 5) + kk0;
        const float* src = w_mid + ((size_t)((c*16 + m)*128 + ci0))*9 + tap;
        short8 v;
#pragma unroll
        for (int e = 0; e < 8; ++e) {
            __hip_bfloat16 h = __float2bfloat16(src[e*9]);
            v[e] = *(short*)&h;
        }
        *(short8*)(wB2 + base) = v;
    } else {
        // halo zeroing: 540,672 elems = 264 blocks x 256 thr x 8 elems
        const int htab[4] = {0, 1, 66, 67};
        int e = (blockIdx.x - 1664)*2048 + t*8;
        short8 z = {0,0,0,0,0,0,0,0};
        if (e < 278528) {
            // top/bottom rows: b x {0,1,66,67} x 68 w x 128 ci
            int hh = e / 8704;               // 68*128 per row
            int rem = e - hh*8704;
            int b = hh >> 2, h = htab[hh & 3];
            *(short8*)(xTp + ((size_t)(b*68 + h)*68)*128 + rem) = z;
        } else {
            // left/right cols: b x rows 2..65 x {0,1,66,67} x 128 ci
            int e2 = e - 278528;             // < 262144
            int g = e2 >> 9;                 // (b, hr) unit = 4*128
            int b = g >> 6, hr = (g & 63) + 2;
            int rem2 = e2 & 511;
            int w = htab[rem2 >> 7], ci = rem2 & 127;
            *(short8*)(xTp + ((size_t)((b*68 + hr)*68 + w))*128 + ci) = z;
        }
    }
}

// ---------------------------------------------------------------------------
// Implicit-GEMM conv — R26 body with ONE change: per-phase lgkmcnt(0) moved
// BEFORE the boundary vmcnt/barrier, so each wave drains its fragment reads
// while others arrive; after release the MFMAs start immediately.
// sched_barrier(0) stays right after the barrier (MFMA hoist fence).
// Fused BN partial stats in the epilogue (R26-proven).
__global__ __launch_bounds__(512, 2) void k_conv(
    const __hip_bfloat16* __restrict__ xTp,
    const __hip_bfloat16* __restrict__ wB2,
    const float* __restrict__ w_pt,
    const float* __restrict__ b_pt,
    float* __restrict__ y,
    float2* __restrict__ partials) {
    extern __shared__ char smem[];
    __hip_bfloat16* Ae = (__hip_bfloat16*)smem;              // 4 x 8192 elems
    __hip_bfloat16* Be = (__hip_bfloat16*)(smem + 65536);    // 4 x 8192 elems

    const int combo = blockIdx.x & 7;      // XCD: one (p, nt) each
    const int p  = combo & 1;
    const int nt = combo >> 1;             // 0..3
    const int mt = blockIdx.x >> 3;        // 0..127 (256 spatial rows each)
    const int dil = 1 + p;

    const int t = threadIdx.x;             // 0..511
    const int lane = t & 63;
    const int wave = t >> 6;               // 0..7
    const int wm = wave >> 2;              // 0..1
    const int wn = wave & 3;               // 0..3
    const int lm = lane & 15, lg = lane >> 4;

    // ---- staging addressing (R21/R24-verbatim) ----
    const int rsub = t >> 2;                              // row 0..127
    const int ksub = (((t & 3) ^ ((t >> 3) & 3)) << 3);   // src-side swizzled slot
    const __hip_bfloat16* abase0;
    const __hip_bfloat16* abase1;
    {
        int s0 = mt*256 + rsub;
        int s1 = s0 + 128;
        abase0 = xTp + ((size_t)(((s0>>12)*68 + ((s0>>6)&63) + 2)*68 + (s0&63) + 2))*128 + ksub;
        abase1 = xTp + ((size_t)(((s1>>12)*68 + ((s1>>6)&63) + 2)*68 + (s1&63) + 2))*128 + ksub;
    }
    const __hip_bfloat16* bbase = wB2 + (size_t)(p*4 + nt)*(36*8192)
                                + rsub*32 + ksub;

    // ---- ds-read offsets (R21/R24-verbatim swizzle) ----
    const int sslot = (lg ^ ((lm >> 1) & 3)) << 3;
    const int aoffb = (wm*128 + lm)*32 + sslot;     // + i*512 + dbuf*8192
    const int boffb = (wn*64 + lm)*32 + sslot;      // + j*512 + dbuf*8192

    f32x4 acc[8][4];
#pragma unroll
    for (int i = 0; i < 8; ++i)
#pragma unroll
        for (int j = 0; j < 4; ++j) acc[i][j] = (f32x4){0.f, 0.f, 0.f, 0.f};

    // ---- prologue: stage kt0 -> dbuf0, kt1 -> dbuf1 (8 loads), vmcnt(4) ----
    {
        const int t0 = -dil*8832;    // tap 0: kh=-1, kw=-1; ci0 = 0
        gload_lds16(abase0 + t0,      smem           + (0*512 + t)*16);
        gload_lds16(abase1 + t0,      smem           + (1*512 + t)*16);
        gload_lds16(bbase,            smem + 65536   + (0*512 + t)*16);
        gload_lds16(bbase + 4096,     smem + 65536   + (1*512 + t)*16);
        gload_lds16(abase0 + t0 + 32, smem + 16384   + (0*512 + t)*16);
        gload_lds16(abase1 + t0 + 32, smem + 16384   + (1*512 + t)*16);
        gload_lds16(bbase + 8192,     smem + 81920   + (0*512 + t)*16);
        gload_lds16(bbase + 12288,    smem + 81920   + (1*512 + t)*16);
    }
    asm volatile("s_waitcnt vmcnt(4)" ::: "memory");   // kt0 resident, kt1 in flight
    __builtin_amdgcn_s_barrier();
    __builtin_amdgcn_sched_barrier(0);

    // ---- K-loop: kt = 4*vv + ss, 2 phases (q) per ktile ----
#pragma unroll 1
    for (int vv = 0; vv < 9; ++vv) {
        const int q3c = (vv*11) >> 5;
        const int toff_c = dil*128*((q3c - 1)*68 + (vv - 3*q3c - 1));
        const int vn = vv + 1;
        const int q3n = (vn*11) >> 5;
        const int toff_n = dil*128*((q3n - 1)*68 + (vn - 3*q3n - 1));
#pragma unroll
        for (int ss = 0; ss < 4; ++ss) {
            const int d  = ss;                 // dbuf of ktile kt (static)
            const int d2 = (ss + 2) & 3;       // dbuf staged (static)
            const bool do_stage = (vv < 8) || (ss < 2);   // kt+2 < 36
            short8 bf[4];
            short8 af[4];
#pragma unroll
            for (int q = 0; q < 2; ++q) {
                if (q == 0) {
#pragma unroll
                    for (int j = 0; j < 4; ++j)
                        bf[j] = *(const short8*)(Be + d*8192 + boffb + j*512);
                }
#pragma unroll
                for (int ii = 0; ii < 4; ++ii)
                    af[ii] = *(const short8*)(Ae + d*8192 + aoffb + (q*4 + ii)*512);
                if (do_stage) {
                    if (q == 0) {
                        const int aoff = (ss < 2) ? (toff_c + (ss + 2)*32)
                                                  : (toff_n + (ss - 2)*32);
                        gload_lds16(abase0 + aoff, smem + d2*16384 + (0*512 + t)*16);
                        gload_lds16(abase1 + aoff, smem + d2*16384 + (1*512 + t)*16);
                    } else {
                        const size_t bo = (size_t)(4*vv + ss + 2)*8192;
                        gload_lds16(bbase + bo,        smem + 65536 + d2*16384 + (0*512 + t)*16);
                        gload_lds16(bbase + bo + 4096, smem + 65536 + d2*16384 + (1*512 + t)*16);
                    }
                }
                // drain own fragment reads BEFORE the barrier (overlaps with
                // other waves' arrival); then boundary vmcnt; then barrier.
                asm volatile("s_waitcnt lgkmcnt(0)" ::: "memory");
                if (q == 1) {
                    if (ss == 2) {
                        if (vv == 8) asm volatile("s_waitcnt vmcnt(0)" ::: "memory");
                        else         asm volatile("s_waitcnt vmcnt(4)" ::: "memory");
                    } else {
                        asm volatile("s_waitcnt vmcnt(4)" ::: "memory");
                    }
                }
                __builtin_amdgcn_s_barrier();
                __builtin_amdgcn_sched_barrier(0);
                __builtin_amdgcn_s_setprio(1);
#pragma unroll
                for (int ii = 0; ii < 4; ++ii)
#pragma unroll
                    for (int j = 0; j < 4; ++j)
                        acc[q*4 + ii][j] = __builtin_amdgcn_mfma_f32_16x16x32_bf16(
                            af[ii], bf[j], acc[q*4 + ii][j], 0, 0, 0);
                __builtin_amdgcn_s_setprio(0);
            }
        }
    }

    // ---- epilogue: leaky -> *w_pt -> sum over j -> 2 shuffles; fused stats ----
    {
        const int ci_ = lm & 3;
        const int mg  = lm >> 2;                       // m sub-index in lanes
        const int c   = (((nt*4 + wn)*4 + ci_) << 1) + p;
        const float bp = b_pt[c];
        float wpj[4];
#pragma unroll
        for (int j = 0; j < 4; ++j)
            wpj[j] = w_pt[c*16 + j*4 + mg];
        float ts = 0.f, ts2 = 0.f;
#pragma unroll
        for (int i = 0; i < 8; ++i) {
#pragma unroll
            for (int r = 0; r < 4; ++r) {
                float s = 0.f;
#pragma unroll
                for (int j = 0; j < 4; ++j) {
                    float v = acc[i][j][r];
                    v = v >= 0.f ? v : 0.1f*v;
                    s += v * wpj[j];
                }
                s += __shfl_xor(s, 4);
                s += __shfl_xor(s, 8);
                if (mg == 0) {
                    float val = s + bp;
                    int srow = mt*256 + wm*128 + i*16 + lg*4 + r;
                    int b = srow >> 12, hw = srow & 4095;
                    y[(size_t)(b*128 + c)*4096 + hw] = val;
                    ts  += val;
                    ts2 += val*val;
                }
            }
        }
        // reduce over lg (lanes differing in bits 4,5; lm preserved)
        ts  += __shfl_xor(ts, 16);  ts2 += __shfl_xor(ts2, 16);
        ts  += __shfl_xor(ts, 32);  ts2 += __shfl_xor(ts2, 32);
        __syncthreads();                       // K-loop LDS use fully done
        float2* red = (float2*)smem;           // 8 waves x 4 ci
        if (lg == 0 && mg == 0) red[wave*4 + ci_] = make_float2(ts, ts2);
        __syncthreads();
        if (t < 16) {
            int wn_ = t >> 2, ci2 = t & 3;
            float2 a0 = red[(0*4 + wn_)*4 + ci2];    // wm=0 wave
            float2 a1 = red[(1*4 + wn_)*4 + ci2];    // wm=1 wave
            int cc = (((nt*4 + wn_)*4 + ci2) << 1) + p;
            partials[cc*128 + mt] = make_float2(a0.x + a1.x, a0.y + a1.y);
        }
    }
}

// ---------------------------------------------------------------------------
// BN finalize (from 128 per-channel block-partials) + apply + ReLU.
__global__ __launch_bounds__(256) void k_bn_apply(float* __restrict__ y,
                                                  const float2* __restrict__ partials,
                                                  const float* __restrict__ gamma,
                                                  const float* __restrict__ beta) {
    int bid = blockIdx.x;
    int c = (bid >> 2) & 127;
    float s = 0.f, s2 = 0.f;
    const float2* pc = partials + c*128;
#pragma unroll 8
    for (int i = 0; i < 128; ++i) {
        float2 pr = pc[i];
        s += pr.x; s2 += pr.y;
    }
    float mean = s * (1.f/32768.f);
    float var  = s2 * (1.f/32768.f) - mean*mean;
    float scale = gamma[c] * rsqrtf(var + EPSV);
    float shift = beta[c] - mean*scale;
    float4* y4 = (float4*)y;
    int idx = bid*256 + threadIdx.x;
    float4 v = y4[idx];
    v.x = fmaxf(v.x*scale + shift, 0.f);
    v.y = fmaxf(v.y*scale + shift, 0.f);
    v.z = fmaxf(v.z*scale + shift, 0.f);
    v.w = fmaxf(v.w*scale + shift, 0.f);
    y4[idx] = v;
}

// ---------------------------------------------------------------------------
extern "C" void kernel_launch(void* const* d_in, const int* in_sizes, int n_in,
                              void* d_out, int out_size, void* d_ws, size_t ws_size,
                              hipStream_t stream) {
    const float* x     = (const float*)d_in[0];
    const float* w_mid = (const float*)d_in[1];
    const float* w_pt  = (const float*)d_in[2];
    const float* b_pt  = (const float*)d_in[3];
    const float* gamma = (const float*)d_in[4];
    const float* beta  = (const float*)d_in[5];
    float* y = (float*)d_out;

    __hip_bfloat16* wB2 = (__hip_bfloat16*)d_ws;
    __hip_bfloat16* xTp = (__hip_bfloat16*)((char*)d_ws + WB2_BYTES);
    float2* partials    = (float2*)((char*)d_ws + STATS_OFF);

    // opt in to >64 KB dynamic LDS for k_conv (host-side, graph-capture-safe)
    (void)hipFuncSetAttribute((const void*)k_conv,
                              hipFuncAttributeMaxDynamicSharedMemorySize,
                              CONV_LDS_BYTES);

    k_prep<<<1928, 256, 0, stream>>>(x, w_mid, xTp, wB2);
    k_conv<<<1024, 512, CONV_LDS_BYTES, stream>>>(xTp, wB2, w_pt, b_pt, y, partials);
    k_bn_apply<<<4096, 256, 0, stream>>>(y, partials, gamma, beta);
}